// Round 1
// baseline (711.385 us; speedup 1.0000x reference)
//
#include <hip/hip_runtime.h>
#include <hip/hip_bf16.h>

#define DIM   4096
#define NH    32
#define HD    128
#define BATCH 2
#define SEQ   1024
#define MROWS (BATCH*SEQ)   // 2048

typedef __attribute__((ext_vector_type(8))) short bf16x8;
typedef __attribute__((ext_vector_type(4))) float f32x4;

__device__ inline void gload_lds16(const void* g, void* l) {
  __builtin_amdgcn_global_load_lds(
      (const __attribute__((address_space(1))) void*)g,
      (__attribute__((address_space(3))) void*)l, 16, 0, 0);
}

__device__ inline float bf2f(short b) {
  unsigned u = ((unsigned)(unsigned short)b) << 16;
  return __uint_as_float(u);
}
__device__ inline unsigned short f2bfu(float f) {
  __hip_bfloat16 h = __float2bfloat16(f);
  return *reinterpret_cast<unsigned short*>(&h);
}

// ---------------- fp32 -> bf16 convert (vectorized) ----------------
__global__ void cvt_bf16_kernel(const float* __restrict__ in,
                                unsigned short* __restrict__ out, long n4) {
  long i = blockIdx.x * (long)blockDim.x + threadIdx.x;
  long stride = (long)gridDim.x * blockDim.x;
  for (; i < n4; i += stride) {
    float4 v = ((const float4*)in)[i];
    ushort4 o;
    o.x = f2bfu(v.x); o.y = f2bfu(v.y); o.z = f2bfu(v.z); o.w = f2bfu(v.w);
    ((ushort4*)out)[i] = o;
  }
}

// ---------------- RoPE cos/sin table ----------------
__global__ void rope_table_kernel(float* __restrict__ cosT, float* __restrict__ sinT) {
  int s = blockIdx.x;     // 0..SEQ-1
  int p = threadIdx.x;    // 0..63
  float inv = powf(10000.0f, -((float)(2 * p)) / 128.0f);
  float a = (float)s * inv;
  cosT[s * 64 + p] = cosf(a);
  sinT[s * 64 + p] = sinf(a);
}

// ---------------- RoPE apply (interleaved pairs), in-place on bf16 ----------------
__global__ void rope_apply_kernel(unsigned short* __restrict__ t,
                                  const float* __restrict__ cosT,
                                  const float* __restrict__ sinT) {
  int c = blockIdx.x * blockDim.x + threadIdx.x;  // chunk of 8 bf16 (4 pairs)
  long e = (long)c * 8;
  int row = (int)(e >> 12);       // /DIM
  int col = (int)(e & (DIM - 1));
  int s = row & (SEQ - 1);
  int d = col & (HD - 1);         // multiple of 8
  int p0 = d >> 1;                // multiple of 4
  bf16x8 v = *(bf16x8*)&t[e];
  f32x4 cv = *(const f32x4*)&cosT[s * 64 + p0];
  f32x4 sv = *(const f32x4*)&sinT[s * 64 + p0];
  bf16x8 o;
#pragma unroll
  for (int j = 0; j < 4; ++j) {
    float x0 = bf2f(v[2 * j]);
    float x1 = bf2f(v[2 * j + 1]);
    o[2 * j]     = (short)f2bfu(x0 * cv[j] - x1 * sv[j]);
    o[2 * j + 1] = (short)f2bfu(x0 * sv[j] + x1 * cv[j]);
  }
  *(bf16x8*)&t[e] = o;
}

// ---------------- GEMM: C[m,n] = sum_k A[m,k]*B[n,k] + bias[n] ----------------
// A: MxK row-major bf16, B: NxK row-major bf16 (i.e. x @ W^T), C: MxN (OutT)
// 128x128 tile, BK=32, 4 waves (2x2 of 64x64), m97 structure.
template <typename OutT>
__global__ __launch_bounds__(256) void gemm_bt_kernel(
    const unsigned short* __restrict__ A, const unsigned short* __restrict__ Bw,
    const float* __restrict__ bias, OutT* __restrict__ C, int M, int N, int K) {
  __shared__ unsigned short As[128 * 32];
  __shared__ unsigned short Bs[128 * 32];
  const int t = threadIdx.x;
  const int lane = t & 63;
  const int w = t >> 6;
  const int wr = w >> 1, wc = w & 1;
  const int m0 = blockIdx.y * 128;
  const int n0 = blockIdx.x * 128;

  const int ar0 = t >> 2;           // staging row (chunk 0); chunk 1 adds 64
  const int acol = (t & 3) * 8;
  const unsigned short* Ag0 = A + (size_t)(m0 + ar0) * K + acol;
  const unsigned short* Ag1 = A + (size_t)(m0 + 64 + ar0) * K + acol;
  const unsigned short* Bg0 = Bw + (size_t)(n0 + ar0) * K + acol;
  const unsigned short* Bg1 = Bw + (size_t)(n0 + 64 + ar0) * K + acol;
  unsigned short* Al0 = &As[(size_t)t * 8];
  unsigned short* Al1 = &As[(size_t)(256 + t) * 8];
  unsigned short* Bl0 = &Bs[(size_t)t * 8];
  unsigned short* Bl1 = &Bs[(size_t)(256 + t) * 8];

  f32x4 acc[4][4] = {};

  const int aro = wr * 64 + (lane & 15);
  const int bro = wc * 64 + (lane & 15);
  const int ko = (lane >> 4) * 8;

  for (int k0 = 0; k0 < K; k0 += 32) {
    gload_lds16(Ag0 + k0, Al0);
    gload_lds16(Ag1 + k0, Al1);
    gload_lds16(Bg0 + k0, Bl0);
    gload_lds16(Bg1 + k0, Bl1);
    __syncthreads();
    bf16x8 af[4], bfr[4];
#pragma unroll
    for (int i = 0; i < 4; ++i)
      af[i] = *(const bf16x8*)&As[(aro + i * 16) * 32 + ko];
#pragma unroll
    for (int j = 0; j < 4; ++j)
      bfr[j] = *(const bf16x8*)&Bs[(bro + j * 16) * 32 + ko];
#pragma unroll
    for (int i = 0; i < 4; ++i)
#pragma unroll
      for (int j = 0; j < 4; ++j)
        acc[i][j] = __builtin_amdgcn_mfma_f32_16x16x32_bf16(af[i], bfr[j], acc[i][j], 0, 0, 0);
    __syncthreads();
  }

  const int mrow = m0 + wr * 64 + (lane >> 4) * 4;
  const int ncol = n0 + wc * 64 + (lane & 15);
#pragma unroll
  for (int j = 0; j < 4; ++j) {
    float bj = bias[ncol + j * 16];
#pragma unroll
    for (int i = 0; i < 4; ++i) {
#pragma unroll
      for (int r = 0; r < 4; ++r) {
        float v = acc[i][j][r] + bj;
        if constexpr (sizeof(OutT) == 2) {
          ((unsigned short*)C)[(size_t)(mrow + i * 16 + r) * N + (ncol + j * 16)] = f2bfu(v);
        } else {
          ((float*)C)[(size_t)(mrow + i * 16 + r) * N + (ncol + j * 16)] = v;
        }
      }
    }
  }
}

// ---------------- Flash attention (causal), bf16 in/out ----------------
// grid (S/64, BATCH*NH); 256 threads = 4 waves, each wave owns 16 Q rows.
__global__ __launch_bounds__(256) void flash_attn_kernel(
    const unsigned short* __restrict__ Q, const unsigned short* __restrict__ Kk,
    const unsigned short* __restrict__ V, unsigned short* __restrict__ O) {
  __shared__ unsigned short Ks[64 * 128];
  __shared__ unsigned short Vs[64 * 128];
  __shared__ unsigned short Ps[4][16 * 64];

  const int qt = blockIdx.x;   // q tile (64 rows)
  const int bh = blockIdx.y;   // b*NH + h
  const int b = bh >> 5;
  const int h = bh & 31;
  const int t = threadIdx.x;
  const int lane = t & 63;
  const int w = t >> 6;

  const size_t headoff = (size_t)b * SEQ * DIM + (size_t)h * HD;
  const unsigned short* Qg = Q + headoff;
  const unsigned short* Kg = Kk + headoff;
  const unsigned short* Vg = V + headoff;
  unsigned short* Og = O + headoff;

  const int qrow = qt * 64 + w * 16 + (lane & 15);
  const int ko = (lane >> 4) * 8;
  bf16x8 qf[4];
#pragma unroll
  for (int kb = 0; kb < 4; ++kb)
    qf[kb] = *(const bf16x8*)&Qg[(size_t)qrow * DIM + kb * 32 + ko];

  f32x4 o_acc[8] = {};
  float m_run[4], l_run[4];
#pragma unroll
  for (int r = 0; r < 4; ++r) { m_run[r] = -3.0e38f; l_run[r] = 0.0f; }

  const int srow = t >> 4;
  const int scol = (t & 15) * 8;
  const float SCALE = 0.08838834764831843f;  // 1/sqrt(128)

  for (int kt = 0; kt <= qt; ++kt) {
#pragma unroll
    for (int p = 0; p < 4; ++p) {
      gload_lds16(&Kg[(size_t)(kt * 64 + p * 16 + srow) * DIM + scol], &Ks[(p * 256 + t) * 8]);
      gload_lds16(&Vg[(size_t)(kt * 64 + p * 16 + srow) * DIM + scol], &Vs[(p * 256 + t) * 8]);
    }
    __syncthreads();

    // S = Q K^T  (16 rows x 64 kv per wave)
    f32x4 sc[4] = {};
#pragma unroll
    for (int ct = 0; ct < 4; ++ct) {
#pragma unroll
      for (int kb = 0; kb < 4; ++kb) {
        bf16x8 kf = *(const bf16x8*)&Ks[(ct * 16 + (lane & 15)) * 128 + kb * 32 + ko];
        sc[ct] = __builtin_amdgcn_mfma_f32_16x16x32_bf16(qf[kb], kf, sc[ct], 0, 0, 0);
      }
    }

    // scale + causal mask (diagonal tile only)
#pragma unroll
    for (int ct = 0; ct < 4; ++ct) {
      int kvc = kt * 64 + ct * 16 + (lane & 15);
#pragma unroll
      for (int r = 0; r < 4; ++r) {
        float v = sc[ct][r] * SCALE;
        if (kt == qt) {
          int qr = qt * 64 + w * 16 + (lane >> 4) * 4 + r;
          if (kvc > qr) v = -1.0e9f;
        }
        sc[ct][r] = v;
      }
    }

    // online softmax: row reductions across 16-lane groups
    float scale_f[4];
#pragma unroll
    for (int r = 0; r < 4; ++r) {
      float tmax = fmaxf(fmaxf(sc[0][r], sc[1][r]), fmaxf(sc[2][r], sc[3][r]));
      tmax = fmaxf(tmax, __shfl_xor(tmax, 1));
      tmax = fmaxf(tmax, __shfl_xor(tmax, 2));
      tmax = fmaxf(tmax, __shfl_xor(tmax, 4));
      tmax = fmaxf(tmax, __shfl_xor(tmax, 8));
      float mn = fmaxf(m_run[r], tmax);
      scale_f[r] = __expf(m_run[r] - mn);
      m_run[r] = mn;
    }

    unsigned short* Pw = &Ps[w][0];
#pragma unroll
    for (int r = 0; r < 4; ++r) {
      float rsum = 0.f;
#pragma unroll
      for (int ct = 0; ct < 4; ++ct) {
        float p = __expf(sc[ct][r] - m_run[r]);
        rsum += p;
        Pw[((lane >> 4) * 4 + r) * 64 + ct * 16 + (lane & 15)] = f2bfu(p);
      }
      rsum += __shfl_xor(rsum, 1);
      rsum += __shfl_xor(rsum, 2);
      rsum += __shfl_xor(rsum, 4);
      rsum += __shfl_xor(rsum, 8);
      l_run[r] = l_run[r] * scale_f[r] + rsum;
    }

    // rescale O
#pragma unroll
    for (int nt2 = 0; nt2 < 8; ++nt2)
#pragma unroll
      for (int r = 0; r < 4; ++r)
        o_acc[nt2][r] *= scale_f[r];

    // O += P V
    const short* vsh = (const short*)Vs;
#pragma unroll
    for (int kb2 = 0; kb2 < 2; ++kb2) {
      bf16x8 pa = *(const bf16x8*)&Pw[(lane & 15) * 64 + kb2 * 32 + ko];
#pragma unroll
      for (int nt2 = 0; nt2 < 8; ++nt2) {
        bf16x8 vf;
#pragma unroll
        for (int i = 0; i < 8; ++i)
          vf[i] = vsh[(kb2 * 32 + (lane >> 4) * 8 + i) * 128 + nt2 * 16 + (lane & 15)];
        o_acc[nt2] = __builtin_amdgcn_mfma_f32_16x16x32_bf16(pa, vf, o_acc[nt2], 0, 0, 0);
      }
    }
    __syncthreads();
  }

  // epilogue: O /= l
#pragma unroll
  for (int r = 0; r < 4; ++r) {
    float rl = 1.0f / l_run[r];
    int orow = qt * 64 + w * 16 + (lane >> 4) * 4 + r;
#pragma unroll
    for (int nt2 = 0; nt2 < 8; ++nt2)
      Og[(size_t)orow * DIM + nt2 * 16 + (lane & 15)] = f2bfu(o_acc[nt2][r] * rl);
  }
}

extern "C" void kernel_launch(void* const* d_in, const int* in_sizes, int n_in,
                              void* d_out, int out_size, void* d_ws, size_t ws_size,
                              hipStream_t stream) {
  const float* x  = (const float*)d_in[0];
  const float* wq = (const float*)d_in[1];
  const float* bq = (const float*)d_in[2];
  const float* wk = (const float*)d_in[3];
  const float* bk = (const float*)d_in[4];
  const float* wv = (const float*)d_in[5];
  const float* bv = (const float*)d_in[6];
  const float* wo = (const float*)d_in[7];
  const float* bo = (const float*)d_in[8];
  float* out = (float*)d_out;

  char* ws = (char*)d_ws;
  unsigned short* xb  = (unsigned short*)(ws);                    // 16 MB
  unsigned short* wqb = (unsigned short*)(ws + (16ll  << 20));    // 32 MB
  unsigned short* wkb = (unsigned short*)(ws + (48ll  << 20));
  unsigned short* wvb = (unsigned short*)(ws + (80ll  << 20));
  unsigned short* wob = (unsigned short*)(ws + (112ll << 20));
  unsigned short* qb  = (unsigned short*)(ws + (144ll << 20));    // 16 MB
  unsigned short* kb_ = (unsigned short*)(ws + (160ll << 20));
  unsigned short* vb  = (unsigned short*)(ws + (176ll << 20));
  unsigned short* ab  = (unsigned short*)(ws + (192ll << 20));
  float* cosT = (float*)(ws + (208ll << 20));
  float* sinT = (float*)(ws + (208ll << 20) + (256 << 10));

  // fp32 -> bf16
  cvt_bf16_kernel<<<2048, 256, 0, stream>>>(x,  xb,  (long)MROWS * DIM / 4);
  cvt_bf16_kernel<<<2048, 256, 0, stream>>>(wq, wqb, (long)DIM * DIM / 4);
  cvt_bf16_kernel<<<2048, 256, 0, stream>>>(wk, wkb, (long)DIM * DIM / 4);
  cvt_bf16_kernel<<<2048, 256, 0, stream>>>(wv, wvb, (long)DIM * DIM / 4);
  cvt_bf16_kernel<<<2048, 256, 0, stream>>>(wo, wob, (long)DIM * DIM / 4);

  rope_table_kernel<<<SEQ, 64, 0, stream>>>(cosT, sinT);

  dim3 gg(DIM / 128, MROWS / 128);  // (32, 16)
  gemm_bt_kernel<unsigned short><<<gg, 256, 0, stream>>>(xb, wqb, bq, qb, MROWS, DIM, DIM);
  gemm_bt_kernel<unsigned short><<<gg, 256, 0, stream>>>(xb, wkb, bk, kb_, MROWS, DIM, DIM);
  gemm_bt_kernel<unsigned short><<<gg, 256, 0, stream>>>(xb, wvb, bv, vb, MROWS, DIM, DIM);

  int rope_blocks = (MROWS * DIM / 8) / 256;  // 4096
  rope_apply_kernel<<<rope_blocks, 256, 0, stream>>>(qb, cosT, sinT);
  rope_apply_kernel<<<rope_blocks, 256, 0, stream>>>(kb_, cosT, sinT);

  dim3 ga(SEQ / 64, BATCH * NH);  // (16, 64)
  flash_attn_kernel<<<ga, 256, 0, stream>>>(qb, kb_, vb, ab);

  gemm_bt_kernel<float><<<gg, 256, 0, stream>>>(ab, wob, bo, out, MROWS, DIM, DIM);
}

// Round 2
// 635.231 us; speedup vs baseline: 1.1199x; 1.1199x over previous
//
#include <hip/hip_runtime.h>
#include <hip/hip_bf16.h>

#define DIM   4096
#define NH    32
#define HD    128
#define BATCH 2
#define SEQ   1024
#define MROWS (BATCH*SEQ)   // 2048

typedef __attribute__((ext_vector_type(8))) short bf16x8;
typedef __attribute__((ext_vector_type(4))) short s16x4;
typedef __attribute__((ext_vector_type(4))) float f32x4;

__device__ inline void gload_lds16(const void* g, void* l) {
  __builtin_amdgcn_global_load_lds(
      (const __attribute__((address_space(1))) void*)g,
      (__attribute__((address_space(3))) void*)l, 16, 0, 0);
}

__device__ inline float bf2f(short b) {
  unsigned u = ((unsigned)(unsigned short)b) << 16;
  return __uint_as_float(u);
}
__device__ inline unsigned short f2bfu(float f) {
  __hip_bfloat16 h = __float2bfloat16(f);
  return *reinterpret_cast<unsigned short*>(&h);
}

// ---------------- fp32 -> bf16 convert (vectorized) ----------------
__global__ void cvt_bf16_kernel(const float* __restrict__ in,
                                unsigned short* __restrict__ out, long n4) {
  long i = blockIdx.x * (long)blockDim.x + threadIdx.x;
  long stride = (long)gridDim.x * blockDim.x;
  for (; i < n4; i += stride) {
    float4 v = ((const float4*)in)[i];
    ushort4 o;
    o.x = f2bfu(v.x); o.y = f2bfu(v.y); o.z = f2bfu(v.z); o.w = f2bfu(v.w);
    ((ushort4*)out)[i] = o;
  }
}

// ---------------- RoPE cos/sin table ----------------
__global__ void rope_table_kernel(float* __restrict__ cosT, float* __restrict__ sinT) {
  int s = blockIdx.x;     // 0..SEQ-1
  int p = threadIdx.x;    // 0..63
  float inv = powf(10000.0f, -((float)(2 * p)) / 128.0f);
  float a = (float)s * inv;
  cosT[s * 64 + p] = cosf(a);
  sinT[s * 64 + p] = sinf(a);
}

// ---------------- RoPE apply (interleaved pairs), in-place on bf16 ----------------
__global__ void rope_apply_kernel(unsigned short* __restrict__ t,
                                  const float* __restrict__ cosT,
                                  const float* __restrict__ sinT) {
  int c = blockIdx.x * blockDim.x + threadIdx.x;  // chunk of 8 bf16 (4 pairs)
  long e = (long)c * 8;
  int row = (int)(e >> 12);       // /DIM
  int col = (int)(e & (DIM - 1));
  int s = row & (SEQ - 1);
  int d = col & (HD - 1);         // multiple of 8
  int p0 = d >> 1;                // multiple of 4
  bf16x8 v = *(bf16x8*)&t[e];
  f32x4 cv = *(const f32x4*)&cosT[s * 64 + p0];
  f32x4 sv = *(const f32x4*)&sinT[s * 64 + p0];
  bf16x8 o;
#pragma unroll
  for (int j = 0; j < 4; ++j) {
    float x0 = bf2f(v[2 * j]);
    float x1 = bf2f(v[2 * j + 1]);
    o[2 * j]     = (short)f2bfu(x0 * cv[j] - x1 * sv[j]);
    o[2 * j + 1] = (short)f2bfu(x0 * sv[j] + x1 * cv[j]);
  }
  *(bf16x8*)&t[e] = o;
}

// ---------------- GEMM: C[m,n] = sum_k A[m,k]*B[n,k] + bias[n] ----------------
// A: MxK row-major bf16, B: NxK row-major bf16 (i.e. x @ W^T), C: MxN (OutT)
// 128x128 tile, BK=32, 4 waves (2x2 of 64x64), m97 structure.
template <typename OutT>
__global__ __launch_bounds__(256) void gemm_bt_kernel(
    const unsigned short* __restrict__ A, const unsigned short* __restrict__ Bw,
    const float* __restrict__ bias, OutT* __restrict__ C, int M, int N, int K) {
  __shared__ unsigned short As[128 * 32];
  __shared__ unsigned short Bs[128 * 32];
  const int t = threadIdx.x;
  const int lane = t & 63;
  const int w = t >> 6;
  const int wr = w >> 1, wc = w & 1;
  const int m0 = blockIdx.y * 128;
  const int n0 = blockIdx.x * 128;

  const int ar0 = t >> 2;           // staging row (chunk 0); chunk 1 adds 64
  const int acol = (t & 3) * 8;
  const unsigned short* Ag0 = A + (size_t)(m0 + ar0) * K + acol;
  const unsigned short* Ag1 = A + (size_t)(m0 + 64 + ar0) * K + acol;
  const unsigned short* Bg0 = Bw + (size_t)(n0 + ar0) * K + acol;
  const unsigned short* Bg1 = Bw + (size_t)(n0 + 64 + ar0) * K + acol;
  unsigned short* Al0 = &As[(size_t)t * 8];
  unsigned short* Al1 = &As[(size_t)(256 + t) * 8];
  unsigned short* Bl0 = &Bs[(size_t)t * 8];
  unsigned short* Bl1 = &Bs[(size_t)(256 + t) * 8];

  f32x4 acc[4][4] = {};

  const int aro = wr * 64 + (lane & 15);
  const int bro = wc * 64 + (lane & 15);
  const int ko = (lane >> 4) * 8;

  for (int k0 = 0; k0 < K; k0 += 32) {
    gload_lds16(Ag0 + k0, Al0);
    gload_lds16(Ag1 + k0, Al1);
    gload_lds16(Bg0 + k0, Bl0);
    gload_lds16(Bg1 + k0, Bl1);
    __syncthreads();
    bf16x8 af[4], bfr[4];
#pragma unroll
    for (int i = 0; i < 4; ++i)
      af[i] = *(const bf16x8*)&As[(aro + i * 16) * 32 + ko];
#pragma unroll
    for (int j = 0; j < 4; ++j)
      bfr[j] = *(const bf16x8*)&Bs[(bro + j * 16) * 32 + ko];
#pragma unroll
    for (int i = 0; i < 4; ++i)
#pragma unroll
      for (int j = 0; j < 4; ++j)
        acc[i][j] = __builtin_amdgcn_mfma_f32_16x16x32_bf16(af[i], bfr[j], acc[i][j], 0, 0, 0);
    __syncthreads();
  }

  const int mrow = m0 + wr * 64 + (lane >> 4) * 4;
  const int ncol = n0 + wc * 64 + (lane & 15);
#pragma unroll
  for (int j = 0; j < 4; ++j) {
    float bj = bias[ncol + j * 16];
#pragma unroll
    for (int i = 0; i < 4; ++i) {
#pragma unroll
      for (int r = 0; r < 4; ++r) {
        float v = acc[i][j][r] + bj;
        if constexpr (sizeof(OutT) == 2) {
          ((unsigned short*)C)[(size_t)(mrow + i * 16 + r) * N + (ncol + j * 16)] = f2bfu(v);
        } else {
          ((float*)C)[(size_t)(mrow + i * 16 + r) * N + (ncol + j * 16)] = v;
        }
      }
    }
  }
}

// ---------------- Flash attention v2 (causal), bf16 in/out ----------------
// 256 blocks = 4 qtile-pairs x 64 heads. 256 threads = 4 waves.
// QBLK=128 (wave owns 32 q-rows as 2x16 fragments), KVBLK=64.
// In-block qtile pairing (qt, 7-qt): every block runs exactly 18 kv-tiles.
// K in LDS row-major [64][128] XOR-swizzled (chunk ^= row&7).
// V in LDS TRANSPOSED [128 cols][64 k] XOR-swizzled -> PV B-operand is ds_read_b128.
// P per-wave [32][64] XOR-swizzled.
// T14 async-stage: next tile's K/V global loads issued before compute phase.
__global__ __launch_bounds__(256, 1) void flash_attn_kernel(
    const unsigned short* __restrict__ Q, const unsigned short* __restrict__ Kk,
    const unsigned short* __restrict__ V, unsigned short* __restrict__ O) {
  __shared__ unsigned short Ks[64 * 128];    // 16 KB, swizzled row-major
  __shared__ unsigned short Vt[128 * 64];    // 16 KB, transposed + swizzled
  __shared__ unsigned short Ps[4][32 * 64];  // 16 KB, per-wave P, swizzled

  const int p  = blockIdx.x;   // pair 0..3
  const int bh = blockIdx.y;   // b*NH + h
  const int b  = bh >> 5;
  const int hh = bh & 31;
  const int t    = threadIdx.x;
  const int lane = t & 63;
  const int w    = t >> 6;
  const int np   = lane & 15;   // col-in-fragment
  const int hq   = lane >> 4;   // k-half index 0..3

  const size_t headoff = (size_t)b * SEQ * DIM + (size_t)hh * HD;
  const unsigned short* Qg = Q  + headoff;
  const unsigned short* Kg = Kk + headoff;
  const unsigned short* Vg = V  + headoff;
  unsigned short*       Og = O  + headoff;

  // staging assignment
  const int krow = t >> 2;           // K: thread stages row krow, 32 cols
  const int kc0  = (t & 3) * 32;
  const int vr0  = (t & 15) * 4;     // V: thread stages rows vr0..vr0+4, cols vc0..vc0+8
  const int vc0  = (t >> 4) * 8;

  unsigned short* Pw = &Ps[w][0];
  const float SCALE = 0.08838834764831843f;  // 1/sqrt(128)

  bf16x8 vk[4], vv[4];

#pragma unroll 1
  for (int pass = 0; pass < 2; ++pass) {
    const int qt    = pass ? (7 - p) : p;
    const int nt    = 2 * qt + 2;
    const int qbase = qt * 128 + w * 32;

    // Q fragments: 32 rows (2 x 16) x 128 cols per wave
    bf16x8 qf[2][4];
#pragma unroll
    for (int rb = 0; rb < 2; ++rb)
#pragma unroll
      for (int kb = 0; kb < 4; ++kb)
        qf[rb][kb] = *(const bf16x8*)&Qg[(size_t)(qbase + rb * 16 + np) * DIM + kb * 32 + hq * 8];

    f32x4 acc[2][8] = {};
    float m_run[2][4], l_run[2][4];
#pragma unroll
    for (int rb = 0; rb < 2; ++rb)
#pragma unroll
      for (int r = 0; r < 4; ++r) { m_run[rb][r] = -3.0e38f; l_run[rb][r] = 0.0f; }

    // prefetch tile 0 into regs
    {
      const unsigned short* kp = Kg + (size_t)krow * DIM + kc0;
      const unsigned short* vp = Vg + (size_t)vr0 * DIM + vc0;
#pragma unroll
      for (int jj = 0; jj < 4; ++jj) vk[jj] = *(const bf16x8*)(kp + jj * 8);
#pragma unroll
      for (int jj = 0; jj < 4; ++jj) vv[jj] = *(const bf16x8*)(vp + (size_t)jj * DIM);
    }

#pragma unroll 1
    for (int kt = 0; kt < nt; ++kt) {
      __syncthreads();   // previous tile's LDS reads complete

      // ---- write staged regs to LDS (swizzled) ----
#pragma unroll
      for (int jj = 0; jj < 4; ++jj) {
        int c = (t & 3) * 4 + jj;
        *(bf16x8*)((char*)Ks + krow * 256 + ((c ^ (krow & 7)) << 4)) = vk[jj];
      }
#pragma unroll
      for (int i = 0; i < 8; ++i) {
        int col = vc0 + i;
        s16x4 sv;
        sv[0] = vv[0][i]; sv[1] = vv[1][i]; sv[2] = vv[2][i]; sv[3] = vv[3][i];
        *(s16x4*)((char*)Vt + ((col * 128 + vr0 * 2) ^ ((col & 7) << 4))) = sv;
      }
      __syncthreads();   // LDS tile ready

      // ---- issue next tile's global loads (latency hides under compute) ----
      if (kt + 1 < nt) {
        const unsigned short* kp = Kg + (size_t)((kt + 1) * 64 + krow) * DIM + kc0;
        const unsigned short* vp = Vg + (size_t)((kt + 1) * 64 + vr0) * DIM + vc0;
#pragma unroll
        for (int jj = 0; jj < 4; ++jj) vk[jj] = *(const bf16x8*)(kp + jj * 8);
#pragma unroll
        for (int jj = 0; jj < 4; ++jj) vv[jj] = *(const bf16x8*)(vp + (size_t)jj * DIM);
      }

      // ---- S = Q K^T ----
      f32x4 sc[4][2] = {};
#pragma unroll
      for (int ct = 0; ct < 4; ++ct) {
#pragma unroll
        for (int kb = 0; kb < 4; ++kb) {
          bf16x8 kf = *(const bf16x8*)((char*)Ks + (ct * 16 + np) * 256 +
                                       (((kb * 4 + hq) ^ (np & 7)) << 4));
          sc[ct][0] = __builtin_amdgcn_mfma_f32_16x16x32_bf16(qf[0][kb], kf, sc[ct][0], 0, 0, 0);
          sc[ct][1] = __builtin_amdgcn_mfma_f32_16x16x32_bf16(qf[1][kb], kf, sc[ct][1], 0, 0, 0);
        }
      }

      // ---- scale + causal mask (only diagonal tiles kt >= 2*qt) ----
      const bool maskt = (kt >= 2 * qt);
#pragma unroll
      for (int ct = 0; ct < 4; ++ct) {
        int kvc = kt * 64 + ct * 16 + np;
#pragma unroll
        for (int rb = 0; rb < 2; ++rb)
#pragma unroll
          for (int r = 0; r < 4; ++r) {
            float v = sc[ct][rb][r] * SCALE;
            if (maskt && kvc > qbase + rb * 16 + hq * 4 + r) v = -1.0e9f;
            sc[ct][rb][r] = v;
          }
      }

      // ---- online softmax (row reductions across 16-lane col groups) ----
      float sf[2][4];
#pragma unroll
      for (int rb = 0; rb < 2; ++rb)
#pragma unroll
        for (int r = 0; r < 4; ++r) {
          float tmax = fmaxf(fmaxf(sc[0][rb][r], sc[1][rb][r]),
                             fmaxf(sc[2][rb][r], sc[3][rb][r]));
          tmax = fmaxf(tmax, __shfl_xor(tmax, 1));
          tmax = fmaxf(tmax, __shfl_xor(tmax, 2));
          tmax = fmaxf(tmax, __shfl_xor(tmax, 4));
          tmax = fmaxf(tmax, __shfl_xor(tmax, 8));
          float mn = fmaxf(m_run[rb][r], tmax);
          sf[rb][r] = __expf(m_run[rb][r] - mn);
          m_run[rb][r] = mn;
        }

      // ---- P = exp(S-m), row sums, write P to per-wave LDS (swizzled) ----
#pragma unroll
      for (int rb = 0; rb < 2; ++rb)
#pragma unroll
        for (int r = 0; r < 4; ++r) {
          int prow = rb * 16 + hq * 4 + r;
          int swz = (prow & 7) << 4;
          float rsum = 0.f;
#pragma unroll
          for (int ct = 0; ct < 4; ++ct) {
            float pv = __expf(sc[ct][rb][r] - m_run[rb][r]);
            rsum += pv;
            *(unsigned short*)((char*)Pw + ((prow * 128 + (ct * 16 + np) * 2) ^ swz)) = f2bfu(pv);
          }
          rsum += __shfl_xor(rsum, 1);
          rsum += __shfl_xor(rsum, 2);
          rsum += __shfl_xor(rsum, 4);
          rsum += __shfl_xor(rsum, 8);
          l_run[rb][r] = l_run[rb][r] * sf[rb][r] + rsum;
        }

      // ---- rescale O ----
#pragma unroll
      for (int rb = 0; rb < 2; ++rb)
#pragma unroll
        for (int nt2 = 0; nt2 < 8; ++nt2)
#pragma unroll
          for (int r = 0; r < 4; ++r)
            acc[rb][nt2][r] *= sf[rb][r];

      // ---- O += P V  (B-operand from transposed, swizzled Vt) ----
      // (P write->read is same-wave; LDS pipe is in-order per wave, compiler
      //  inserts lgkmcnt waits — no barrier needed.)
#pragma unroll
      for (int kb2 = 0; kb2 < 2; ++kb2) {
        bf16x8 pa0 = *(const bf16x8*)((char*)Pw +
            (((0 * 16 + np) * 128 + kb2 * 64 + hq * 16) ^ ((np & 7) << 4)));
        bf16x8 pa1 = *(const bf16x8*)((char*)Pw +
            (((1 * 16 + np) * 128 + kb2 * 64 + hq * 16) ^ ((np & 7) << 4)));
#pragma unroll
        for (int nt2 = 0; nt2 < 8; ++nt2) {
          int col = nt2 * 16 + np;
          bf16x8 vf = *(const bf16x8*)((char*)Vt +
              ((col * 128 + kb2 * 64 + hq * 16) ^ ((col & 7) << 4)));
          acc[0][nt2] = __builtin_amdgcn_mfma_f32_16x16x32_bf16(pa0, vf, acc[0][nt2], 0, 0, 0);
          acc[1][nt2] = __builtin_amdgcn_mfma_f32_16x16x32_bf16(pa1, vf, acc[1][nt2], 0, 0, 0);
        }
      }
    }

    // ---- epilogue: O /= l ----
#pragma unroll
    for (int rb = 0; rb < 2; ++rb)
#pragma unroll
      for (int r = 0; r < 4; ++r) {
        float rl = 1.0f / l_run[rb][r];
        int orow = qbase + rb * 16 + hq * 4 + r;
#pragma unroll
        for (int nt2 = 0; nt2 < 8; ++nt2)
          Og[(size_t)orow * DIM + nt2 * 16 + np] = f2bfu(acc[rb][nt2][r] * rl);
      }
  }
}

extern "C" void kernel_launch(void* const* d_in, const int* in_sizes, int n_in,
                              void* d_out, int out_size, void* d_ws, size_t ws_size,
                              hipStream_t stream) {
  const float* x  = (const float*)d_in[0];
  const float* wq = (const float*)d_in[1];
  const float* bq = (const float*)d_in[2];
  const float* wk = (const float*)d_in[3];
  const float* bk = (const float*)d_in[4];
  const float* wv = (const float*)d_in[5];
  const float* bv = (const float*)d_in[6];
  const float* wo = (const float*)d_in[7];
  const float* bo = (const float*)d_in[8];
  float* out = (float*)d_out;

  char* ws = (char*)d_ws;
  unsigned short* xb  = (unsigned short*)(ws);                    // 16 MB
  unsigned short* wqb = (unsigned short*)(ws + (16ll  << 20));    // 32 MB
  unsigned short* wkb = (unsigned short*)(ws + (48ll  << 20));
  unsigned short* wvb = (unsigned short*)(ws + (80ll  << 20));
  unsigned short* wob = (unsigned short*)(ws + (112ll << 20));
  unsigned short* qb  = (unsigned short*)(ws + (144ll << 20));    // 16 MB
  unsigned short* kb_ = (unsigned short*)(ws + (160ll << 20));
  unsigned short* vb  = (unsigned short*)(ws + (176ll << 20));
  unsigned short* ab  = (unsigned short*)(ws + (192ll << 20));
  float* cosT = (float*)(ws + (208ll << 20));
  float* sinT = (float*)(ws + (208ll << 20) + (256 << 10));

  // fp32 -> bf16
  cvt_bf16_kernel<<<2048, 256, 0, stream>>>(x,  xb,  (long)MROWS * DIM / 4);
  cvt_bf16_kernel<<<2048, 256, 0, stream>>>(wq, wqb, (long)DIM * DIM / 4);
  cvt_bf16_kernel<<<2048, 256, 0, stream>>>(wk, wkb, (long)DIM * DIM / 4);
  cvt_bf16_kernel<<<2048, 256, 0, stream>>>(wv, wvb, (long)DIM * DIM / 4);
  cvt_bf16_kernel<<<2048, 256, 0, stream>>>(wo, wob, (long)DIM * DIM / 4);

  rope_table_kernel<<<SEQ, 64, 0, stream>>>(cosT, sinT);

  dim3 gg(DIM / 128, MROWS / 128);  // (32, 16)
  gemm_bt_kernel<unsigned short><<<gg, 256, 0, stream>>>(xb, wqb, bq, qb, MROWS, DIM, DIM);
  gemm_bt_kernel<unsigned short><<<gg, 256, 0, stream>>>(xb, wkb, bk, kb_, MROWS, DIM, DIM);
  gemm_bt_kernel<unsigned short><<<gg, 256, 0, stream>>>(xb, wvb, bv, vb, MROWS, DIM, DIM);

  int rope_blocks = (MROWS * DIM / 8) / 256;  // 4096
  rope_apply_kernel<<<rope_blocks, 256, 0, stream>>>(qb, cosT, sinT);
  rope_apply_kernel<<<rope_blocks, 256, 0, stream>>>(kb_, cosT, sinT);

  dim3 ga(4, BATCH * NH);  // 4 qtile-pairs x 64 heads = 256 blocks
  flash_attn_kernel<<<ga, 256, 0, stream>>>(qb, kb_, vb, ab);

  gemm_bt_kernel<float><<<gg, 256, 0, stream>>>(ab, wob, bo, out, MROWS, DIM, DIM);
}

// Round 3
// 560.113 us; speedup vs baseline: 1.2701x; 1.1341x over previous
//
#include <hip/hip_runtime.h>
#include <hip/hip_bf16.h>

#define DIM   4096
#define NH    32
#define HD    128
#define BATCH 2
#define SEQ   1024
#define MROWS (BATCH*SEQ)   // 2048
#define LDQ   12288         // fused qkv row stride

typedef __attribute__((ext_vector_type(8))) short bf16x8;
typedef __attribute__((ext_vector_type(4))) short s16x4;
typedef __attribute__((ext_vector_type(4))) float f32x4;

__device__ inline void gload_lds16(const void* g, void* l) {
  __builtin_amdgcn_global_load_lds(
      (const __attribute__((address_space(1))) void*)g,
      (__attribute__((address_space(3))) void*)l, 16, 0, 0);
}

__device__ inline float bf2f(short b) {
  unsigned u = ((unsigned)(unsigned short)b) << 16;
  return __uint_as_float(u);
}
__device__ inline unsigned short f2bfu(float f) {
  __hip_bfloat16 h = __float2bfloat16(f);
  return *reinterpret_cast<unsigned short*>(&h);
}

// ---------------- fp32 -> bf16 convert (vectorized) ----------------
__global__ void cvt_bf16_kernel(const float* __restrict__ in,
                                unsigned short* __restrict__ out, long n4) {
  long i = blockIdx.x * (long)blockDim.x + threadIdx.x;
  long stride = (long)gridDim.x * blockDim.x;
  for (; i < n4; i += stride) {
    float4 v = ((const float4*)in)[i];
    ushort4 o;
    o.x = f2bfu(v.x); o.y = f2bfu(v.y); o.z = f2bfu(v.z); o.w = f2bfu(v.w);
    ((ushort4*)out)[i] = o;
  }
}

// ---------------- bias concat (bq|bk|bv -> 12288) ----------------
__global__ void concat3_kernel(const float* __restrict__ a, const float* __restrict__ b,
                               const float* __restrict__ c, float* __restrict__ o) {
  int i = blockIdx.x * blockDim.x + threadIdx.x;
  if (i < 4096) o[i] = a[i];
  else if (i < 8192) o[i] = b[i - 4096];
  else if (i < 12288) o[i] = c[i - 8192];
}

// ---------------- RoPE cos/sin table ----------------
__global__ void rope_table_kernel(float* __restrict__ cosT, float* __restrict__ sinT) {
  int s = blockIdx.x;     // 0..SEQ-1
  int p = threadIdx.x;    // 0..63
  float inv = powf(10000.0f, -((float)(2 * p)) / 128.0f);
  float a = (float)s * inv;
  cosT[s * 64 + p] = cosf(a);
  sinT[s * 64 + p] = sinf(a);
}

// ---------------- RoPE apply on fused qkv (first 8192 cols of each row) --------
__global__ void rope_apply_kernel(unsigned short* __restrict__ qkv,
                                  const float* __restrict__ cosT,
                                  const float* __restrict__ sinT) {
  int c = blockIdx.x * blockDim.x + threadIdx.x;  // chunk of 8 bf16
  long e = (long)c * 8;                           // within 2048 x 8192 region
  int row = (int)(e >> 13);
  int col = (int)(e & 8191);
  int s = row & (SEQ - 1);
  int d = col & (HD - 1);
  int p0 = d >> 1;
  unsigned short* p = qkv + (size_t)row * LDQ + col;
  bf16x8 v = *(bf16x8*)p;
  f32x4 cv = *(const f32x4*)&cosT[s * 64 + p0];
  f32x4 sv = *(const f32x4*)&sinT[s * 64 + p0];
  bf16x8 o;
#pragma unroll
  for (int j = 0; j < 4; ++j) {
    float x0 = bf2f(v[2 * j]);
    float x1 = bf2f(v[2 * j + 1]);
    o[2 * j]     = (short)f2bfu(x0 * cv[j] - x1 * sv[j]);
    o[2 * j + 1] = (short)f2bfu(x0 * sv[j] + x1 * cv[j]);
  }
  *(bf16x8*)p = o;
}

// ---------------- Pipelined GEMM: C[m,n] = sum_k A[m,k]*B[n,k] + bias[n] -------
// BM=256, BN=128, BK=64. 512 threads = 8 waves (2M x 4N), per-wave 128x32.
// Double-buffered LDS (96KB), counted vmcnt (T4): tile t+2 staged mid-iteration,
// end-of-iter waits vmcnt(6) = tile t+1 landed, t+2's 6 loads stay in flight.
// XOR-swizzle (row&7) on K-chunks, applied source-side + read-side (rule #21).
__device__ __forceinline__ void stage_tile(
    const unsigned short* __restrict__ A, const unsigned short* __restrict__ Bw,
    unsigned short* Asl, unsigned short* Bsl,
    int m0, int n0, int K, int kbase, int t) {
#pragma unroll
  for (int j = 0; j < 4; ++j) {
    int ci = j * 512 + t;
    int r = ci >> 3, c = ci & 7;
    gload_lds16(A + (size_t)(m0 + r) * K + kbase + ((c ^ (r & 7)) << 3), Asl + ci * 8);
  }
#pragma unroll
  for (int j = 0; j < 2; ++j) {
    int ci = j * 512 + t;
    int r = ci >> 3, c = ci & 7;
    gload_lds16(Bw + (size_t)(n0 + r) * K + kbase + ((c ^ (r & 7)) << 3), Bsl + ci * 8);
  }
}

template <typename OutT>
__global__ __launch_bounds__(512, 2) void gemm_bt_p_kernel(
    const unsigned short* __restrict__ A, const unsigned short* __restrict__ Bw,
    const float* __restrict__ bias, OutT* __restrict__ C, int M, int N, int K) {
  __shared__ unsigned short As[2][256 * 64];   // 64 KB
  __shared__ unsigned short Bs[2][128 * 64];   // 32 KB
  const int t = threadIdx.x;
  const int lane = t & 63;
  const int w = t >> 6;
  const int wm = w >> 2, wn = w & 3;
  const int np = lane & 15, hq = lane >> 4;

  // T1: bijective XCD swizzle (nwg % 8 == 0 by construction)
  int bid = blockIdx.y * gridDim.x + blockIdx.x;
  int nwg = gridDim.x * gridDim.y;
  int sb = (bid & 7) * (nwg >> 3) + (bid >> 3);
  int bx = sb % gridDim.x, by = sb / gridDim.x;
  const int m0 = by * 256, n0 = bx * 128;
  const int NT = K >> 6;

  stage_tile(A, Bw, As[0], Bs[0], m0, n0, K, 0, t);
  stage_tile(A, Bw, As[1], Bs[1], m0, n0, K, 64, t);

  f32x4 acc[8][2] = {};

  asm volatile("s_waitcnt vmcnt(6)" ::: "memory");   // tile 0 landed
  __builtin_amdgcn_s_barrier();

  int cur = 0;
  for (int kt = 0; kt < NT; ++kt) {
    const unsigned short* Asl = As[cur];
    const unsigned short* Bsl = Bs[cur];
    // ---- k-half 0: frags + 16 MFMA ----
    bf16x8 a0[8], b0[2];
#pragma unroll
    for (int i = 0; i < 8; ++i)
      a0[i] = *(const bf16x8*)&Asl[(wm * 128 + i * 16 + np) * 64 + ((hq ^ (np & 7)) << 3)];
#pragma unroll
    for (int j = 0; j < 2; ++j)
      b0[j] = *(const bf16x8*)&Bsl[(wn * 32 + j * 16 + np) * 64 + ((hq ^ (np & 7)) << 3)];
    __builtin_amdgcn_s_setprio(1);
#pragma unroll
    for (int i = 0; i < 8; ++i)
#pragma unroll
      for (int j = 0; j < 2; ++j)
        acc[i][j] = __builtin_amdgcn_mfma_f32_16x16x32_bf16(a0[i], b0[j], acc[i][j], 0, 0, 0);
    __builtin_amdgcn_s_setprio(0);
    // ---- k-half 1 frags ----
    bf16x8 a1[8], b1[2];
#pragma unroll
    for (int i = 0; i < 8; ++i)
      a1[i] = *(const bf16x8*)&Asl[(wm * 128 + i * 16 + np) * 64 + (((4 + hq) ^ (np & 7)) << 3)];
#pragma unroll
    for (int j = 0; j < 2; ++j)
      b1[j] = *(const bf16x8*)&Bsl[(wn * 32 + j * 16 + np) * 64 + (((4 + hq) ^ (np & 7)) << 3)];
    asm volatile("s_waitcnt lgkmcnt(0)" ::: "memory");  // my reads of buf[cur] done
    __builtin_amdgcn_s_barrier();                       // everyone's reads done
    if (kt + 2 < NT)
      stage_tile(A, Bw, As[cur], Bs[cur], m0, n0, K, (kt + 2) << 6, t);  // overwrite safe
    __builtin_amdgcn_s_setprio(1);
#pragma unroll
    for (int i = 0; i < 8; ++i)
#pragma unroll
      for (int j = 0; j < 2; ++j)
        acc[i][j] = __builtin_amdgcn_mfma_f32_16x16x32_bf16(a1[i], b1[j], acc[i][j], 0, 0, 0);
    __builtin_amdgcn_s_setprio(0);
    if (kt + 2 < NT) {
      asm volatile("s_waitcnt vmcnt(6)" ::: "memory");  // tile t+1 landed; t+2 in flight
    } else {
      asm volatile("s_waitcnt vmcnt(0)" ::: "memory");
    }
    __builtin_amdgcn_s_barrier();
    cur ^= 1;
  }

  // ---- epilogue: bias + store ----
  const int orow0 = m0 + wm * 128 + hq * 4;
  const int ocol0 = n0 + wn * 32 + np;
#pragma unroll
  for (int j = 0; j < 2; ++j) {
    float bj = bias[ocol0 + j * 16];
#pragma unroll
    for (int i = 0; i < 8; ++i) {
#pragma unroll
      for (int r = 0; r < 4; ++r) {
        float v = acc[i][j][r] + bj;
        size_t off = (size_t)(orow0 + i * 16 + r) * N + (ocol0 + j * 16);
        if constexpr (sizeof(OutT) == 2)
          ((unsigned short*)C)[off] = f2bfu(v);
        else
          ((float*)C)[off] = v;
      }
    }
  }
}

// ---------------- Flash attention (causal), reads fused qkv (stride LDQ) -------
__global__ __launch_bounds__(256, 1) void flash_attn_kernel(
    const unsigned short* __restrict__ QKV, unsigned short* __restrict__ O) {
  __shared__ unsigned short Ks[64 * 128];    // swizzled row-major
  __shared__ unsigned short Vt[128 * 64];    // transposed + swizzled
  __shared__ unsigned short Ps[4][32 * 64];  // per-wave P, swizzled

  const int p  = blockIdx.x;   // pair 0..3
  const int bh = blockIdx.y;   // b*NH + h
  const int b  = bh >> 5;
  const int hh = bh & 31;
  const int t    = threadIdx.x;
  const int lane = t & 63;
  const int w    = t >> 6;
  const int np   = lane & 15;
  const int hq   = lane >> 4;

  const size_t rowbase = (size_t)b * SEQ * LDQ;
  const unsigned short* Qg = QKV + rowbase + (size_t)hh * HD;
  const unsigned short* Kg = QKV + rowbase + 4096 + (size_t)hh * HD;
  const unsigned short* Vg = QKV + rowbase + 8192 + (size_t)hh * HD;
  unsigned short* Og = O + (size_t)b * SEQ * DIM + (size_t)hh * HD;

  const int krow = t >> 2;
  const int kc0  = (t & 3) * 32;
  const int vr0  = (t & 15) * 4;
  const int vc0  = (t >> 4) * 8;

  unsigned short* Pw = &Ps[w][0];
  const float SCALE = 0.08838834764831843f;  // 1/sqrt(128)

  bf16x8 vk[4], vv[4];

#pragma unroll 1
  for (int pass = 0; pass < 2; ++pass) {
    const int qt    = pass ? (7 - p) : p;
    const int nt    = 2 * qt + 2;
    const int qbase = qt * 128 + w * 32;

    bf16x8 qf[2][4];
#pragma unroll
    for (int rb = 0; rb < 2; ++rb)
#pragma unroll
      for (int kb = 0; kb < 4; ++kb)
        qf[rb][kb] = *(const bf16x8*)&Qg[(size_t)(qbase + rb * 16 + np) * LDQ + kb * 32 + hq * 8];

    f32x4 acc[2][8] = {};
    float m_run[2][4], l_run[2][4];
#pragma unroll
    for (int rb = 0; rb < 2; ++rb)
#pragma unroll
      for (int r = 0; r < 4; ++r) { m_run[rb][r] = -3.0e38f; l_run[rb][r] = 0.0f; }

    {
      const unsigned short* kp = Kg + (size_t)krow * LDQ + kc0;
      const unsigned short* vp = Vg + (size_t)vr0 * LDQ + vc0;
#pragma unroll
      for (int jj = 0; jj < 4; ++jj) vk[jj] = *(const bf16x8*)(kp + jj * 8);
#pragma unroll
      for (int jj = 0; jj < 4; ++jj) vv[jj] = *(const bf16x8*)(vp + (size_t)jj * LDQ);
    }

#pragma unroll 1
    for (int kt = 0; kt < nt; ++kt) {
      __syncthreads();

#pragma unroll
      for (int jj = 0; jj < 4; ++jj) {
        int c = (t & 3) * 4 + jj;
        *(bf16x8*)((char*)Ks + krow * 256 + ((c ^ (krow & 7)) << 4)) = vk[jj];
      }
#pragma unroll
      for (int i = 0; i < 8; ++i) {
        int col = vc0 + i;
        s16x4 sv;
        sv[0] = vv[0][i]; sv[1] = vv[1][i]; sv[2] = vv[2][i]; sv[3] = vv[3][i];
        *(s16x4*)((char*)Vt + ((col * 128 + vr0 * 2) ^ ((col & 7) << 4))) = sv;
      }
      __syncthreads();

      if (kt + 1 < nt) {
        const unsigned short* kp = Kg + (size_t)((kt + 1) * 64 + krow) * LDQ + kc0;
        const unsigned short* vp = Vg + (size_t)((kt + 1) * 64 + vr0) * LDQ + vc0;
#pragma unroll
        for (int jj = 0; jj < 4; ++jj) vk[jj] = *(const bf16x8*)(kp + jj * 8);
#pragma unroll
        for (int jj = 0; jj < 4; ++jj) vv[jj] = *(const bf16x8*)(vp + (size_t)jj * LDQ);
      }

      f32x4 sc[4][2] = {};
#pragma unroll
      for (int ct = 0; ct < 4; ++ct) {
#pragma unroll
        for (int kb = 0; kb < 4; ++kb) {
          bf16x8 kf = *(const bf16x8*)((char*)Ks + (ct * 16 + np) * 256 +
                                       (((kb * 4 + hq) ^ (np & 7)) << 4));
          sc[ct][0] = __builtin_amdgcn_mfma_f32_16x16x32_bf16(qf[0][kb], kf, sc[ct][0], 0, 0, 0);
          sc[ct][1] = __builtin_amdgcn_mfma_f32_16x16x32_bf16(qf[1][kb], kf, sc[ct][1], 0, 0, 0);
        }
      }

      const bool maskt = (kt >= 2 * qt);
#pragma unroll
      for (int ct = 0; ct < 4; ++ct) {
        int kvc = kt * 64 + ct * 16 + np;
#pragma unroll
        for (int rb = 0; rb < 2; ++rb)
#pragma unroll
          for (int r = 0; r < 4; ++r) {
            float v = sc[ct][rb][r] * SCALE;
            if (maskt && kvc > qbase + rb * 16 + hq * 4 + r) v = -1.0e9f;
            sc[ct][rb][r] = v;
          }
      }

      float sf[2][4];
#pragma unroll
      for (int rb = 0; rb < 2; ++rb)
#pragma unroll
        for (int r = 0; r < 4; ++r) {
          float tmax = fmaxf(fmaxf(sc[0][rb][r], sc[1][rb][r]),
                             fmaxf(sc[2][rb][r], sc[3][rb][r]));
          tmax = fmaxf(tmax, __shfl_xor(tmax, 1));
          tmax = fmaxf(tmax, __shfl_xor(tmax, 2));
          tmax = fmaxf(tmax, __shfl_xor(tmax, 4));
          tmax = fmaxf(tmax, __shfl_xor(tmax, 8));
          float mn = fmaxf(m_run[rb][r], tmax);
          sf[rb][r] = __expf(m_run[rb][r] - mn);
          m_run[rb][r] = mn;
        }

#pragma unroll
      for (int rb = 0; rb < 2; ++rb)
#pragma unroll
        for (int r = 0; r < 4; ++r) {
          int prow = rb * 16 + hq * 4 + r;
          int swz = (prow & 7) << 4;
          float rsum = 0.f;
#pragma unroll
          for (int ct = 0; ct < 4; ++ct) {
            float pv = __expf(sc[ct][rb][r] - m_run[rb][r]);
            rsum += pv;
            *(unsigned short*)((char*)Pw + ((prow * 128 + (ct * 16 + np) * 2) ^ swz)) = f2bfu(pv);
          }
          rsum += __shfl_xor(rsum, 1);
          rsum += __shfl_xor(rsum, 2);
          rsum += __shfl_xor(rsum, 4);
          rsum += __shfl_xor(rsum, 8);
          l_run[rb][r] = l_run[rb][r] * sf[rb][r] + rsum;
        }

#pragma unroll
      for (int rb = 0; rb < 2; ++rb)
#pragma unroll
        for (int nt2 = 0; nt2 < 8; ++nt2)
#pragma unroll
          for (int r = 0; r < 4; ++r)
            acc[rb][nt2][r] *= sf[rb][r];

#pragma unroll
      for (int kb2 = 0; kb2 < 2; ++kb2) {
        bf16x8 pa0 = *(const bf16x8*)((char*)Pw +
            (((0 * 16 + np) * 128 + kb2 * 64 + hq * 16) ^ ((np & 7) << 4)));
        bf16x8 pa1 = *(const bf16x8*)((char*)Pw +
            (((1 * 16 + np) * 128 + kb2 * 64 + hq * 16) ^ ((np & 7) << 4)));
#pragma unroll
        for (int nt2 = 0; nt2 < 8; ++nt2) {
          int col = nt2 * 16 + np;
          bf16x8 vf = *(const bf16x8*)((char*)Vt +
              ((col * 128 + kb2 * 64 + hq * 16) ^ ((col & 7) << 4)));
          acc[0][nt2] = __builtin_amdgcn_mfma_f32_16x16x32_bf16(pa0, vf, acc[0][nt2], 0, 0, 0);
          acc[1][nt2] = __builtin_amdgcn_mfma_f32_16x16x32_bf16(pa1, vf, acc[1][nt2], 0, 0, 0);
        }
      }
    }

#pragma unroll
    for (int rb = 0; rb < 2; ++rb)
#pragma unroll
      for (int r = 0; r < 4; ++r) {
        float rl = 1.0f / l_run[rb][r];
        int orow = qbase + rb * 16 + hq * 4 + r;
#pragma unroll
        for (int nt2 = 0; nt2 < 8; ++nt2)
          Og[(size_t)orow * DIM + nt2 * 16 + np] = f2bfu(acc[rb][nt2][r] * rl);
      }
  }
}

extern "C" void kernel_launch(void* const* d_in, const int* in_sizes, int n_in,
                              void* d_out, int out_size, void* d_ws, size_t ws_size,
                              hipStream_t stream) {
  const float* x  = (const float*)d_in[0];
  const float* wq = (const float*)d_in[1];
  const float* bq = (const float*)d_in[2];
  const float* wk = (const float*)d_in[3];
  const float* bk = (const float*)d_in[4];
  const float* wv = (const float*)d_in[5];
  const float* bv = (const float*)d_in[6];
  const float* wo = (const float*)d_in[7];
  const float* bo = (const float*)d_in[8];
  float* out = (float*)d_out;

  char* ws = (char*)d_ws;
  unsigned short* wqkvb = (unsigned short*)(ws);                  // 96 MB [12288][4096]
  unsigned short* wob   = (unsigned short*)(ws + (96ll  << 20));  // 32 MB
  unsigned short* xb    = (unsigned short*)(ws + (128ll << 20));  // 16 MB
  unsigned short* qkv   = (unsigned short*)(ws + (144ll << 20));  // 48 MB [2048][12288]
  unsigned short* ab    = (unsigned short*)(ws + (192ll << 20));  // 16 MB
  float* biasqkv = (float*)(ws + (208ll << 20));                  // 48 KB
  float* cosT    = (float*)(ws + (208ll << 20) + (64  << 10));    // 256 KB
  float* sinT    = (float*)(ws + (208ll << 20) + (320 << 10));    // 256 KB

  // fp32 -> bf16 (weights packed: wq|wk|wv contiguous rows)
  cvt_bf16_kernel<<<2048, 256, 0, stream>>>(x,  xb, (long)MROWS * DIM / 4);
  cvt_bf16_kernel<<<2048, 256, 0, stream>>>(wq, wqkvb,                       (long)DIM * DIM / 4);
  cvt_bf16_kernel<<<2048, 256, 0, stream>>>(wk, wqkvb + (size_t)DIM * DIM,   (long)DIM * DIM / 4);
  cvt_bf16_kernel<<<2048, 256, 0, stream>>>(wv, wqkvb + 2 * (size_t)DIM * DIM,(long)DIM * DIM / 4);
  cvt_bf16_kernel<<<2048, 256, 0, stream>>>(wo, wob, (long)DIM * DIM / 4);

  concat3_kernel<<<48, 256, 0, stream>>>(bq, bk, bv, biasqkv);
  rope_table_kernel<<<SEQ, 64, 0, stream>>>(cosT, sinT);

  // fused QKV GEMM: [2048,4096] x [12288,4096]^T -> [2048,12288]
  dim3 gq(LDQ / 128, MROWS / 256);  // (96, 8) = 768 blocks
  gemm_bt_p_kernel<unsigned short><<<gq, 512, 0, stream>>>(xb, wqkvb, biasqkv, qkv,
                                                           MROWS, LDQ, DIM);

  // RoPE over Q|K halves (first 8192 cols of each qkv row)
  rope_apply_kernel<<<(MROWS * 8192 / 8) / 256, 256, 0, stream>>>(qkv, cosT, sinT);

  dim3 ga(4, BATCH * NH);  // 4 qtile-pairs x 64 heads
  flash_attn_kernel<<<ga, 256, 0, stream>>>(qkv, ab);

  // output GEMM: [2048,4096] x [4096,4096]^T -> fp32 out
  dim3 go(DIM / 128, MROWS / 256);  // (32, 8) = 256 blocks
  gemm_bt_p_kernel<float><<<go, 512, 0, stream>>>(ab, wob, bo, out, MROWS, DIM, DIM);
}